// Round 6
// baseline (366.841 us; speedup 1.0000x reference)
//
#include <hip/hip_runtime.h>

#define CRF_B 512
#define CRF_S 512
#define CRF_T 64
#define CRF_MID 256   // forward computes A_0..A_MID ; backward computes Bv_MID

typedef float f2 __attribute__((ext_vector_type(2)));

// Two waves per batch element (block = 128 threads) — R1's proven skeleton +
// R1's depth-2 logits prefetch (best measured). R6 replaces the inner engine:
//
//  OLD (R0..R5): 64x v_readlane -> SGPR -> 64x scalar FMA. All five rounds
//  cluster at 650-1170 cyc/step vs ~300 issue-bound; R5 removed global-load
//  latency structurally and got WORSE -> the engine itself is the cost
//  (readlane issue rate + VALU->SGPR->VALU wait states).
//
//  NEW: broadcast via LDS uniform-address ds_read_b64 pairs (no readlane, no
//  SGPR crossings; renorm exponent from broadcast bc0.x with VALU bit ops) +
//  v_pk_fma_f32 packed fp32 FMA (2 MACs/inst — the instruction behind the
//  157.3 TF fp32 spec). ~32 reads + 32 pk_fma ~= 85 insts/step ~= 190 cyc
//  issue. Inline-asm "v" constraints also pin et2[] into true VGPRs
//  (R0/R4/R5 show VGPR_Count~52 -> et was parked in AGPRs).
//
// Linear-space power-of-2 renorm per chain (proven absmax=0): k = exponent of
// element 0 of the broadcast vector, scale 2^-k folded off the critical path;
// K accumulates, logZ = log(v) + (Kf+Kb)*ln2.
__global__ __launch_bounds__(128, 1) void crf_fused_kernel(
    const float* __restrict__ logits,   // [B,S,T]
    const int*   __restrict__ tags_raw, // [B,S] int32 OR int64 (runtime-detected)
    const float* __restrict__ trans,    // [T,T]
    const float* __restrict__ start_t,  // [T]
    const float* __restrict__ end_t,    // [T]
    float* __restrict__ out)            // [1], pre-zeroed
{
    const int b   = blockIdx.x;
    const int tid = threadIdx.x;
    const int j   = tid & 63;   // lane
    const int w   = tid >> 6;   // wave id: 0 = forward, 1 = backward

    __shared__ __align__(16) float abuf[2][CRF_T];  // per-wave broadcast buffer
    __shared__ float shBv[CRF_T];  // backward vector at MID
    __shared__ float shNum[2];     // per-wave numerator partial
    __shared__ int   shK[2];       // per-wave renorm exponent sum

    // ---- detect int64 tags: little-endian pairs -> odd 32-bit words all 0 ----
    bool is64 = true;
    #pragma unroll
    for (int ww = 1; ww < 64; ww += 2) is64 = is64 && (tags_raw[ww] == 0);

    const float* lb = logits + (size_t)b * CRF_S * CRF_T;
    const int tbase = b * CRF_S;

    // ---- numerator: 128 threads, positions i = tid, tid+128, ... ----
    float num = 0.f;
    #pragma unroll
    for (int kk = 0; kk < CRF_S / 128; ++kk) {
        int i = kk * 128 + tid;
        int ti = is64 ? tags_raw[(size_t)(tbase + i) * 2] : tags_raw[tbase + i];
        num += lb[i * CRF_T + ti];                       // emission, all i
        if (i == 0) {
            num += start_t[ti];
        } else {
            int tp = is64 ? tags_raw[(size_t)(tbase + i - 1) * 2]
                          : tags_raw[tbase + i - 1];
            num += trans[tp * CRF_T + ti];               // transition, i>=1
        }
        if (i == CRF_S - 1) num += end_t[ti];
    }
    #pragma unroll
    for (int m = 32; m >= 1; m >>= 1) num += __shfl_xor(num, m, 64);
    if (j == 0) shNum[w] = num;

    // one packed-FMA step: ACC += BC * ET   (2 fp32 MACs, exact)
    #define PKFMA(ACC, BC, ET)                                                 \
        asm("v_pk_fma_f32 %0, %1, %2, %0" : "+v"(ACC) : "v"(BC), "v"(ET))

    int K = 0;
    float vec;  // this wave's end-of-loop 64-vector element

    if (w == 0) {
        // ================= forward: A_0 .. A_MID =================
        f2 et2[CRF_T / 2];   // ET column j as pairs: {exp(tr[2q][j]), exp(tr[2q+1][j])}
        #pragma unroll
        for (int q = 0; q < CRF_T / 2; ++q) {
            et2[q].x = __expf(trans[(2 * q) * CRF_T + j]);
            et2[q].y = __expf(trans[(2 * q + 1) * CRF_T + j]);
        }
        const f2* ab2 = (const f2*)abuf[0];

        float a = __expf(start_t[j] + lb[j]);     // A_0
        float elog = __expf(lb[1 * CRF_T + j]);   // exp(logits[1]) for step 1
        float lg_next = lb[2 * CRF_T + j];        // logits[2] in flight (depth 2)

        #pragma unroll 2
        for (int i = 1; i <= CRF_MID; ++i) {
            abuf[0][j] = a;                       // ds_write; LDS pipe is in-order

            f2 b0 = ab2[0];                       // broadcast pair {a0, a1}
            // renorm from a[0]'s exponent — all-VALU, no readfirstlane
            int k = (int)(__float_as_uint(b0.x) >> 23) - 127;
            K += k;
            float mult = elog * __int_as_float((unsigned)(127 - k) << 23);  // elog*2^-k

            f2 c0 = {0.f, 0.f}, c1 = {0.f, 0.f}, c2 = {0.f, 0.f}, c3 = {0.f, 0.f};
            PKFMA(c0, b0, et2[0]);
            #pragma unroll
            for (int q = 1; q < CRF_T / 2; ++q) {   // q = 1..31, fully unrolled
                f2 bq = ab2[q];
                if ((q & 3) == 0)      { PKFMA(c0, bq, et2[q]); }
                else if ((q & 3) == 1) { PKFMA(c1, bq, et2[q]); }
                else if ((q & 3) == 2) { PKFMA(c2, bq, et2[q]); }
                else                   { PKFMA(c3, bq, et2[q]); }
            }
            f2 r = (c0 + c1) + (c2 + c3);
            a = (r.x + r.y) * mult;                // A_i

            elog = __expf(lg_next);                // exp(logits[i+1])
            lg_next = lb[(i + 2) * CRF_T + j];     // max idx 258 < 512
        }
        vec = a;   // A_MID[j], scaled by 2^-K
    } else {
        // ================= backward: Bv_{S-1} .. Bv_MID =================
        f2 et2[CRF_T / 2];   // ET row j as pairs: {exp(tr[j][2q]), exp(tr[j][2q+1])}
        #pragma unroll
        for (int q = 0; q < CRF_T / 2; ++q) {
            et2[q].x = __expf(trans[j * CRF_T + 2 * q]);
            et2[q].y = __expf(trans[j * CRF_T + 2 * q + 1]);
        }
        const f2* ab2 = (const f2*)abuf[1];

        float bv = __expf(end_t[j]);                       // Bv_{S-1}
        float elog = __expf(lb[(CRF_S - 1) * CRF_T + j]);  // exp(logits[511]) for i=510
        float lg_next = lb[(CRF_S - 2) * CRF_T + j];       // logits[510] in flight

        #pragma unroll 2
        for (int i = CRF_S - 2; i >= CRF_MID; --i) {
            float c = bv * elog;                  // unscaled; scale applied post-sum
            abuf[1][j] = c;                       // ds_write; in-order LDS pipe

            f2 b0 = ab2[0];
            int k = (int)(__float_as_uint(b0.x) >> 23) - 127;   // exponent of c[0]
            K += k;
            float scale = __int_as_float((unsigned)(127 - k) << 23);  // 2^-k

            f2 c0 = {0.f, 0.f}, c1 = {0.f, 0.f}, c2 = {0.f, 0.f}, c3 = {0.f, 0.f};
            PKFMA(c0, b0, et2[0]);
            #pragma unroll
            for (int q = 1; q < CRF_T / 2; ++q) {   // q = 1..31, fully unrolled
                f2 bq = ab2[q];
                if ((q & 3) == 0)      { PKFMA(c0, bq, et2[q]); }
                else if ((q & 3) == 1) { PKFMA(c1, bq, et2[q]); }
                else if ((q & 3) == 2) { PKFMA(c2, bq, et2[q]); }
                else                   { PKFMA(c3, bq, et2[q]); }
            }
            f2 r = (c0 + c1) + (c2 + c3);
            bv = (r.x + r.y) * scale;             // Bv_i

            elog = __expf(lg_next);                // exp(logits[i])
            lg_next = lb[(i - 2) * CRF_T + j];     // min idx 254 >= 0
        }
        vec = bv;  // Bv_MID[j], scaled by 2^-K
    }

    if (j == 0) shK[w] = K;
    if (w == 1) shBv[j] = vec;
    __syncthreads();

    if (w == 0) {
        // ---- Z = A_MID . Bv_MID ----
        float v = vec * shBv[j];
        #pragma unroll
        for (int m = 32; m >= 1; m >>= 1) v += __shfl_xor(v, m, 64);
        if (j == 0) {
            float logZ = __logf(v) + (float)(shK[0] + shK[1]) * 0.69314718055994531f;
            atomicAdd(out, (shNum[0] + shNum[1]) - logZ);
        }
    }
}

extern "C" void kernel_launch(void* const* d_in, const int* in_sizes, int n_in,
                              void* d_out, int out_size, void* d_ws, size_t ws_size,
                              hipStream_t stream) {
    const float* logits  = (const float*)d_in[0];
    const int*   tags    = (const int*)d_in[1];
    // d_in[2] = mask — all ones by construction, unused
    const float* trans   = (const float*)d_in[3];
    const float* start_t = (const float*)d_in[4];
    const float* end_t   = (const float*)d_in[5];
    float* out = (float*)d_out;

    hipMemsetAsync(out, 0, sizeof(float) * (size_t)out_size, stream);
    crf_fused_kernel<<<dim3(CRF_B), dim3(128), 0, stream>>>(
        logits, tags, trans, start_t, end_t, out);
}

// Round 7
// 208.496 us; speedup vs baseline: 1.7595x; 1.7595x over previous
//
#include <hip/hip_runtime.h>

#define CRF_B 512
#define CRF_S 512
#define CRF_T 64
#define CRF_MID 256   // forward computes A_0..A_MID ; backward computes Bv_MID

// R7: 1024 INDEPENDENT single-wave workgroups — bid<512: forward chain for
// batch bid; bid>=512: backward chain for batch bid-512. Rationale: the
// identical readlane engine measured 646 cyc/step in 1-wave blocks (R0) vs
// 916 in 2-wave blocks (R1); R5 ruled out memory latency. Hypothesis: waves
// of one workgroup co-reside on the same SIMD(s) (per-block slots start at
// SIMD0) and fight for the issue port, while single-wave blocks spread
// 1/SIMD. Splitting fwd/bwd into separate blocks recovers R0's per-wave rate
// for both chains. Blocks b and b+512 share an XCD (512 % 8 == 0) -> shared
// L2 for that batch's logits.
//
// Cross-block combine via d_ws (device-scope atomics + threadfence, guide
// G12/G16): each block publishes its 64-vector + K, fences, bumps the batch
// counter; the SECOND finisher computes Z = A_MID . Bv_MID and adds -logZ.
// The forward block also computes/adds the numerator.
//
// ws layout: int counter[512] | per (b,dir): { float vec[64]; int K; pad[3] }
// (stride 68 floats). Counters memset to 0 each launch.
//
// Chain bodies are R0/R1-verbatim (best-measured codegen): readlane broadcast
// + 4-accumulator FMA, depth-2 logits prefetch, power-of-2 renorm (absmax 0).
__global__ __launch_bounds__(64, 1) void crf_fused_kernel(
    const float* __restrict__ logits,   // [B,S,T]
    const int*   __restrict__ tags_raw, // [B,S] int32 OR int64 (runtime-detected)
    const float* __restrict__ trans,    // [T,T]
    const float* __restrict__ start_t,  // [T]
    const float* __restrict__ end_t,    // [T]
    float* __restrict__ out,            // [1], pre-zeroed
    float* __restrict__ ws)             // workspace, counters pre-zeroed
{
    const int bid = blockIdx.x;
    const int b   = bid & (CRF_B - 1);
    const int dir = bid >> 9;          // 0 = forward, 1 = backward
    const int j   = threadIdx.x;

    int*   counters = (int*)ws;
    float* slot_my  = ws + 512 + (size_t)(b * 2 + dir) * 68;
    float* slot_ot  = ws + 512 + (size_t)(b * 2 + (dir ^ 1)) * 68;

    const float* lb = logits + (size_t)b * CRF_S * CRF_T;

    int K = 0;
    float vec;      // this block's end-of-chain 64-vector element
    float num = 0.f;

    if (dir == 0) {
        // ---- detect int64 tags: little-endian pairs -> odd words all 0 ----
        bool is64 = true;
        #pragma unroll
        for (int ww = 1; ww < 64; ww += 2) is64 = is64 && (tags_raw[ww] == 0);
        const int tbase = b * CRF_S;

        // ---- numerator: per-lane gathers over positions i = j, j+64, ... ----
        #pragma unroll
        for (int kk = 0; kk < CRF_S / 64; ++kk) {
            int i = kk * 64 + j;
            int ti = is64 ? tags_raw[(size_t)(tbase + i) * 2] : tags_raw[tbase + i];
            num += lb[i * CRF_T + ti];                       // emission, all i
            if (i == 0) {
                num += start_t[ti];
            } else {
                int tp = is64 ? tags_raw[(size_t)(tbase + i - 1) * 2]
                              : tags_raw[tbase + i - 1];
                num += trans[tp * CRF_T + ti];               // transition, i>=1
            }
            if (i == CRF_S - 1) num += end_t[ti];
        }
        #pragma unroll
        for (int m = 32; m >= 1; m >>= 1) num += __shfl_xor(num, m, 64);

        // ================= forward: A_0 .. A_MID =================
        float et[CRF_T];
        #pragma unroll
        for (int t = 0; t < CRF_T; ++t) et[t] = __expf(trans[t * CRF_T + j]); // ET col j

        float a = __expf(start_t[j] + lb[j]);     // A_0
        float elog = __expf(lb[1 * CRF_T + j]);   // exp(logits[1]) for step 1
        float lg_next = lb[2 * CRF_T + j];        // logits[2] in flight (depth 2)

        #pragma unroll 2
        for (int i = 1; i <= CRF_MID; ++i) {
            unsigned mf = (unsigned)__builtin_amdgcn_readfirstlane(__float_as_int(a));
            int k = (int)(mf >> 23) - 127;
            K += k;
            float mult = elog * __int_as_float((unsigned)(127 - k) << 23);  // elog*2^-k

            int ai = __float_as_int(a);
            float f0 = 0.f, f1 = 0.f, f2 = 0.f, f3 = 0.f;
            #pragma unroll
            for (int t = 0; t < CRF_T; t += 4) {
                f0 = fmaf(__int_as_float(__builtin_amdgcn_readlane(ai, t + 0)), et[t + 0], f0);
                f1 = fmaf(__int_as_float(__builtin_amdgcn_readlane(ai, t + 1)), et[t + 1], f1);
                f2 = fmaf(__int_as_float(__builtin_amdgcn_readlane(ai, t + 2)), et[t + 2], f2);
                f3 = fmaf(__int_as_float(__builtin_amdgcn_readlane(ai, t + 3)), et[t + 3], f3);
            }
            a = ((f0 + f1) + (f2 + f3)) * mult;   // A_i

            elog = __expf(lg_next);               // exp(logits[i+1])
            lg_next = lb[(i + 2) * CRF_T + j];    // max idx 258 < 512
        }
        vec = a;   // A_MID[j], scaled by 2^-K
    } else {
        // ================= backward: Bv_{S-1} .. Bv_MID =================
        float et[CRF_T];
        #pragma unroll
        for (int t = 0; t < CRF_T; ++t) et[t] = __expf(trans[j * CRF_T + t]); // ET row j

        float bv = __expf(end_t[j]);                       // Bv_{S-1}
        float elog = __expf(lb[(CRF_S - 1) * CRF_T + j]);  // exp(logits[511]) for i=510
        float lg_next = lb[(CRF_S - 2) * CRF_T + j];       // logits[510] in flight

        #pragma unroll 2
        for (int i = CRF_S - 2; i >= CRF_MID; --i) {
            unsigned mb = (unsigned)__builtin_amdgcn_readfirstlane(__float_as_int(bv));
            int k = (int)(mb >> 23) - 127;
            K += k;
            float c = bv * (elog * __int_as_float((unsigned)(127 - k) << 23));

            int ci = __float_as_int(c);
            float f0 = 0.f, f1 = 0.f, f2 = 0.f, f3 = 0.f;
            #pragma unroll
            for (int t = 0; t < CRF_T; t += 4) {
                f0 = fmaf(__int_as_float(__builtin_amdgcn_readlane(ci, t + 0)), et[t + 0], f0);
                f1 = fmaf(__int_as_float(__builtin_amdgcn_readlane(ci, t + 1)), et[t + 1], f1);
                f2 = fmaf(__int_as_float(__builtin_amdgcn_readlane(ci, t + 2)), et[t + 2], f2);
                f3 = fmaf(__int_as_float(__builtin_amdgcn_readlane(ci, t + 3)), et[t + 3], f3);
            }
            bv = (f0 + f1) + (f2 + f3);           // Bv_i

            elog = __expf(lg_next);               // exp(logits[i])
            lg_next = lb[(i - 2) * CRF_T + j];    // min idx 254 >= 0
        }
        vec = bv;  // Bv_MID[j], scaled by 2^-K
    }

    // ---- publish my half (device-scope stores), fence, bump counter ----
    atomicExch(&slot_my[j], vec);
    if (j == 0) atomicExch((int*)&slot_my[CRF_T], K);
    __threadfence();

    int old = 0;
    if (j == 0) old = atomicAdd(&counters[b], 1);
    old = __shfl(old, 0, 64);

    if (old == 1) {
        // ---- I'm the second finisher: combine Z = A_MID . Bv_MID ----
        __threadfence();
        float ov = atomicAdd(&slot_ot[j], 0.0f);            // partner vec[j]
        int oK = 0;
        if (j == 0) oK = atomicAdd((int*)&slot_ot[CRF_T], 0);
        oK = __shfl(oK, 0, 64);

        float v = vec * ov;
        #pragma unroll
        for (int m = 32; m >= 1; m >>= 1) v += __shfl_xor(v, m, 64);

        if (j == 0) {
            float logZ = __logf(v) + (float)(K + oK) * 0.69314718055994531f;
            atomicAdd(out, -logZ);
        }
    }

    if (dir == 0 && j == 0) atomicAdd(out, num);
}

extern "C" void kernel_launch(void* const* d_in, const int* in_sizes, int n_in,
                              void* d_out, int out_size, void* d_ws, size_t ws_size,
                              hipStream_t stream) {
    const float* logits  = (const float*)d_in[0];
    const int*   tags    = (const int*)d_in[1];
    // d_in[2] = mask — all ones by construction, unused
    const float* trans   = (const float*)d_in[3];
    const float* start_t = (const float*)d_in[4];
    const float* end_t   = (const float*)d_in[5];
    float* out = (float*)d_out;
    float* ws  = (float*)d_ws;

    hipMemsetAsync(out, 0, sizeof(float) * (size_t)out_size, stream);
    hipMemsetAsync(ws, 0, 512 * sizeof(int), stream);   // batch counters only
    crf_fused_kernel<<<dim3(2 * CRF_B), dim3(64), 0, stream>>>(
        logits, tags, trans, start_t, end_t, out, ws);
}